// Round 2
// baseline (257.709 us; speedup 1.0000x reference)
//
#include <hip/hip_runtime.h>
#include <hip/hip_bf16.h>
#include <stdint.h>

#define D_H 128

typedef __bf16 bf16_t;
typedef unsigned short u16;
typedef bf16_t bf16x8 __attribute__((ext_vector_type(8)));
typedef bf16_t bf16x4 __attribute__((ext_vector_type(4)));
typedef float  f32x4  __attribute__((ext_vector_type(4)));

// ------- fused pre-pass: 4-way privatized countrank + W prep ---------------
__global__ void k_pre(const int* __restrict__ dst, int* __restrict__ cnt4,
                      u16* __restrict__ rank, int E, int Nn, int gcr,
                      const float* __restrict__ W1, bf16_t* __restrict__ W1h,
                      bf16_t* __restrict__ W1l, int K1,
                      const float* __restrict__ W2, bf16_t* __restrict__ W2h,
                      bf16_t* __restrict__ W2l, int K2) {
    int bx = (int)blockIdx.x;
    if (bx < gcr) {
        int e = bx * 256 + threadIdx.x;
        if (e < E) {
            int d = dst[e];
            rank[e] = (u16)atomicAdd(&cnt4[(bx & 3) * Nn + d], 1);
        }
        return;
    }
    int id = (bx - gcr) * 256 + threadIdx.x;
    int n1 = K1 * 128;
    if (id < n1) {
        int k = id >> 7, n = id & 127;
        float w = W1[id];
        bf16_t h = (bf16_t)w;
        W1h[(size_t)n * K1 + k] = h;
        W1l[(size_t)n * K1 + k] = (bf16_t)(w - (float)h);
    } else if (id < n1 + K2 * 128) {
        int id2 = id - n1;
        int k = id2 >> 7, n = id2 & 127;
        float w = W2[id2];
        bf16_t h = (bf16_t)w;
        W2h[(size_t)n * K2 + k] = h;
        W2l[(size_t)n * K2 + k] = (bf16_t)(w - (float)h);
    }
}

// ---------------- exclusive scan; scan1 sums the 4 copies + emits dis ------
__global__ __launch_bounds__(1024) void k_scan1(const int* __restrict__ cnt4,
                                                int* __restrict__ out,
                                                int* __restrict__ bsums,
                                                float* __restrict__ dis, int N) {
    __shared__ int tmp[1024];
    int t = threadIdx.x;
    int i = blockIdx.x * 1024 + t;
    int v = 0;
    if (i < N) {
        v = cnt4[i] + cnt4[N + i] + cnt4[2 * N + i] + cnt4[3 * N + i];
        dis[i] = 1.0f / sqrtf((float)(v + 1));
    }
    tmp[t] = v;
    __syncthreads();
    for (int d = 1; d < 1024; d <<= 1) {
        int x = (t >= d) ? tmp[t - d] : 0;
        __syncthreads();
        tmp[t] += x;
        __syncthreads();
    }
    if (i < N) out[i] = tmp[t] - v;
    if (t == 1023) bsums[blockIdx.x] = tmp[t];
}

__global__ void k_scan2(int* __restrict__ bsums, int nb) {
    __shared__ int tmp[64];
    int t = threadIdx.x;
    int v = (t < nb) ? bsums[t] : 0;
    tmp[t] = v;
    __syncthreads();
    for (int d = 1; d < 64; d <<= 1) {
        int x = (t >= d) ? tmp[t - d] : 0;
        __syncthreads();
        tmp[t] += x;
        __syncthreads();
    }
    if (t < nb) bsums[t] = tmp[t] - v;
}

__global__ __launch_bounds__(1024) void k_scan3(int* __restrict__ off,
                                                const int* __restrict__ bsums,
                                                const int* __restrict__ cnt4,
                                                int* __restrict__ offc,
                                                int N, int E) {
    int i = blockIdx.x * 1024 + threadIdx.x;
    if (i < N) {
        int o = off[i] + bsums[blockIdx.x];
        off[i] = o;
        int c0 = cnt4[i], c1 = cnt4[N + i], c2 = cnt4[2 * N + i];
        offc[i]         = o;
        offc[N + i]     = o + c0;
        offc[2 * N + i] = o + c0 + c1;
        offc[3 * N + i] = o + c0 + c1 + c2;
    }
    if (i == 0) off[N] = E;
}

// ---------------- MFMA GEMM tiles: BM=64, BN=64, 256 thr = 4 waves --------
// v10: SINGLE LDS buffer (20KB — keeps R0 occupancy) + T14 issue-early/
// write-late reg prefetch: next tile's global loads issue BEFORE current
// tile's ds_read+MFMA, so HBM latency hides under compute + 2 barriers.
#define LDK 40
#define FILL_PER 2

// layer-1 (fp32 A, hi/lo split in-kernel, K=256) + atomic-free CSR fill
__global__ __launch_bounds__(256) void k_mm1fill(
        const float* __restrict__ Af,
        const bf16_t* __restrict__ Wh, const bf16_t* __restrict__ Wl,
        const float* __restrict__ dis, bf16_t* __restrict__ Cb,
        int N, int K,
        const int* __restrict__ src, const int* __restrict__ dst,
        const int* __restrict__ offc, const u16* __restrict__ rank,
        u16* __restrict__ csr16, int E, int totThreads) {
    __shared__ bf16_t AsH[64][LDK];
    __shared__ bf16_t AsL[64][LDK];
    __shared__ bf16_t BsH[64][LDK];
    __shared__ bf16_t BsL[64][LDK];

    const int t    = threadIdx.x;
    const int lane = t & 63;
    const int wave = t >> 6;            // 0..3
    const int row0 = ((int)blockIdx.x >> 1) * 64;
    const int col0 = ((int)blockIdx.x & 1) * 64;
    const int wm   = (wave & 1) * 32;
    const int wn   = (wave >> 1) * 32;
    const int fm   = lane & 15;
    const int fq   = lane >> 4;

    const int arow = t >> 3;            // 0..31 (A: rows arow, arow+32)
    const int ac4  = t & 7;             // float4 column group
    const int brow = t >> 2;            // 0..63
    const int bc8  = t & 3;             // bf16x8 column group

    // ---- fill prologue: resolve scatter addresses ----
    const int g = (int)blockIdx.x * 256 + t;
    int epos[FILL_PER];
    u16 esrc[FILL_PER];
#pragma unroll
    for (int i = 0; i < FILL_PER; i++) {
        int e = g + i * totThreads;
        if (e < E) {
            int d    = dst[e];
            int copy = (e >> 8) & 3;
            epos[i] = offc[copy * N + d] + (int)rank[e];
            esrc[i] = (u16)src[e];
        } else {
            epos[i] = -1;
            esrc[i] = 0;
        }
    }

    f32x4 acc[2][2] = {};

    float4 va[2];
    bf16x8 vbh, vbl;

    auto loadA = [&](int k0) {
#pragma unroll
        for (int i = 0; i < 2; i++) {
            int gr = row0 + arow + i * 32;
            va[i] = make_float4(0.f, 0.f, 0.f, 0.f);
            if (gr < N) va[i] = *(const float4*)(Af + (size_t)gr * 256 + k0 + ac4 * 4);
        }
    };
    auto loadB = [&](int k0) {
        vbh = *(const bf16x8*)(Wh + (size_t)(col0 + brow) * 256 + k0 + bc8 * 8);
        vbl = *(const bf16x8*)(Wl + (size_t)(col0 + brow) * 256 + k0 + bc8 * 8);
    };
    auto stage = [&]() {
#pragma unroll
        for (int i = 0; i < 2; i++) {
            float4 v = va[i];
            bf16_t h0 = (bf16_t)v.x, h1 = (bf16_t)v.y, h2 = (bf16_t)v.z, h3 = (bf16_t)v.w;
            *(bf16x4*)&AsH[arow + i * 32][ac4 * 4] = (bf16x4){h0, h1, h2, h3};
            *(bf16x4*)&AsL[arow + i * 32][ac4 * 4] =
                (bf16x4){(bf16_t)(v.x - (float)h0), (bf16_t)(v.y - (float)h1),
                         (bf16_t)(v.z - (float)h2), (bf16_t)(v.w - (float)h3)};
        }
        *(bf16x8*)&BsH[brow][bc8 * 8] = vbh;
        *(bf16x8*)&BsL[brow][bc8 * 8] = vbl;
    };
    auto compute = [&]() {
        bf16x8 ah[2], al[2], bh[2], bl[2];
#pragma unroll
        for (int i = 0; i < 2; i++) {
            ah[i] = *(const bf16x8*)&AsH[wm + i * 16 + fm][fq * 8];
            al[i] = *(const bf16x8*)&AsL[wm + i * 16 + fm][fq * 8];
            bh[i] = *(const bf16x8*)&BsH[wn + i * 16 + fm][fq * 8];
            bl[i] = *(const bf16x8*)&BsL[wn + i * 16 + fm][fq * 8];
        }
#pragma unroll
        for (int mi = 0; mi < 2; mi++)
#pragma unroll
            for (int ni = 0; ni < 2; ni++) {
                acc[mi][ni] = __builtin_amdgcn_mfma_f32_16x16x32_bf16(ah[mi], bh[ni], acc[mi][ni], 0, 0, 0);
                acc[mi][ni] = __builtin_amdgcn_mfma_f32_16x16x32_bf16(ah[mi], bl[ni], acc[mi][ni], 0, 0, 0);
                acc[mi][ni] = __builtin_amdgcn_mfma_f32_16x16x32_bf16(al[mi], bh[ni], acc[mi][ni], 0, 0, 0);
            }
    };

    loadA(0); loadB(0);                 // tile 0 in flight
#pragma unroll
    for (int tt = 0; tt < 8; tt++) {
        __syncthreads();                // prev compute's ds_reads done
        stage();                        // vmcnt wait lands here (issued 1 iter ago)
        __syncthreads();
        if (tt + 1 < 8) { loadA((tt + 1) * 32); loadB((tt + 1) * 32); }  // fire next
        compute();                      // hides the in-flight loads
    }

#pragma unroll
    for (int mi = 0; mi < 2; mi++)
#pragma unroll
        for (int r = 0; r < 4; r++) {
            int grow = row0 + wm + mi * 16 + fq * 4 + r;
            if (grow < N) {
                float dr = dis[grow];
#pragma unroll
                for (int ni = 0; ni < 2; ni++)
                    Cb[(size_t)grow * D_H + col0 + wn + ni * 16 + fm] = (bf16_t)(dr * acc[mi][ni][r]);
            }
        }

    // ---- fill epilogue: scattered 2B stores, fire and forget ----
#pragma unroll
    for (int i = 0; i < FILL_PER; i++)
        if (epos[i] >= 0) csr16[epos[i]] = esrc[i];
}

// layer-2 (bf16 hi/lo A, K=128), same single-buffer + reg-prefetch structure
__global__ __launch_bounds__(256) void k_mm2(const bf16_t* __restrict__ Ah,
                                             const bf16_t* __restrict__ Al,
                                             const bf16_t* __restrict__ Wh,
                                             const bf16_t* __restrict__ Wl,
                                             const float* __restrict__ dis,
                                             bf16_t* __restrict__ Cb,
                                             int N, int K) {
    __shared__ bf16_t AsH[64][LDK];
    __shared__ bf16_t AsL[64][LDK];
    __shared__ bf16_t BsH[64][LDK];
    __shared__ bf16_t BsL[64][LDK];

    const int t    = threadIdx.x;
    const int lane = t & 63;
    const int wave = t >> 6;
    const int row0 = ((int)blockIdx.x >> 1) * 64;
    const int col0 = ((int)blockIdx.x & 1) * 64;
    const int wm   = (wave & 1) * 32;
    const int wn   = (wave >> 1) * 32;
    const int fm   = lane & 15;
    const int fq   = lane >> 4;

    const int brow = t >> 2;            // 0..63
    const int bc8  = t & 3;

    f32x4 acc[2][2] = {};

    bf16x8 vah, val, vbh, vbl;

    auto loadAB = [&](int k0) {
        int gr = row0 + brow;
        vah = (bf16x8){}; val = (bf16x8){};
        if (gr < N) {
            vah = *(const bf16x8*)(Ah + (size_t)gr * 128 + k0 + bc8 * 8);
            val = *(const bf16x8*)(Al + (size_t)gr * 128 + k0 + bc8 * 8);
        }
        vbh = *(const bf16x8*)(Wh + (size_t)(col0 + brow) * 128 + k0 + bc8 * 8);
        vbl = *(const bf16x8*)(Wl + (size_t)(col0 + brow) * 128 + k0 + bc8 * 8);
    };
    auto stage = [&]() {
        *(bf16x8*)&AsH[brow][bc8 * 8] = vah;
        *(bf16x8*)&AsL[brow][bc8 * 8] = val;
        *(bf16x8*)&BsH[brow][bc8 * 8] = vbh;
        *(bf16x8*)&BsL[brow][bc8 * 8] = vbl;
    };
    auto compute = [&]() {
        bf16x8 ah[2], al[2], bh[2], bl[2];
#pragma unroll
        for (int i = 0; i < 2; i++) {
            ah[i] = *(const bf16x8*)&AsH[wm + i * 16 + fm][fq * 8];
            al[i] = *(const bf16x8*)&AsL[wm + i * 16 + fm][fq * 8];
            bh[i] = *(const bf16x8*)&BsH[wn + i * 16 + fm][fq * 8];
            bl[i] = *(const bf16x8*)&BsL[wn + i * 16 + fm][fq * 8];
        }
#pragma unroll
        for (int mi = 0; mi < 2; mi++)
#pragma unroll
            for (int ni = 0; ni < 2; ni++) {
                acc[mi][ni] = __builtin_amdgcn_mfma_f32_16x16x32_bf16(ah[mi], bh[ni], acc[mi][ni], 0, 0, 0);
                acc[mi][ni] = __builtin_amdgcn_mfma_f32_16x16x32_bf16(ah[mi], bl[ni], acc[mi][ni], 0, 0, 0);
                acc[mi][ni] = __builtin_amdgcn_mfma_f32_16x16x32_bf16(al[mi], bh[ni], acc[mi][ni], 0, 0, 0);
            }
    };

    loadAB(0);
#pragma unroll
    for (int tt = 0; tt < 4; tt++) {
        __syncthreads();
        stage();
        __syncthreads();
        if (tt + 1 < 4) loadAB((tt + 1) * 32);
        compute();
    }

#pragma unroll
    for (int mi = 0; mi < 2; mi++)
#pragma unroll
        for (int r = 0; r < 4; r++) {
            int grow = row0 + wm + mi * 16 + fq * 4 + r;
            if (grow < N) {
                float dr = dis[grow];
#pragma unroll
                for (int ni = 0; ni < 2; ni++)
                    Cb[(size_t)grow * D_H + col0 + wn + ni * 16 + fm] = (bf16_t)(dr * acc[mi][ni][r]);
            }
        }
}

// ---------------- aggregation (16 lanes/node x bf16x8 = 16B/lane) ----------
// v10: 8-deep gather unroll (was 4) — more memory-level parallelism per slot.
__global__ __launch_bounds__(256) void k_agg(const bf16_t* __restrict__ Hb,
                                             const float* __restrict__ dis,
                                             const int* __restrict__ off,
                                             const u16* __restrict__ csr16,
                                             const float4* __restrict__ bias4,
                                             float4* __restrict__ outF,
                                             bf16_t* __restrict__ outH,
                                             bf16_t* __restrict__ outL,
                                             int N, int mode) {
    const int slot = threadIdx.x >> 4;           // 0..15: node slot
    const int lane = threadIdx.x & 15;           // feature group (8 bf16 = 16B)
    const int node = blockIdx.x * 16 + slot;
    if (node >= N) return;

    const bf16_t* Hrow = Hb + (size_t)lane * 8;

    float a0[8], a1[8], a2[8], a3[8];
    {
        bf16x8 v = *(const bf16x8*)(Hrow + (size_t)node * D_H);
#pragma unroll
        for (int j = 0; j < 8; j++) { a0[j] = (float)v[j]; a1[j] = 0.f; a2[j] = 0.f; a3[j] = 0.f; }
    }

    int p  = off[node];
    int p1 = off[node + 1];

    for (; p + 8 <= p1; p += 8) {
        int s0 = (int)csr16[p + 0], s1 = (int)csr16[p + 1];
        int s2 = (int)csr16[p + 2], s3 = (int)csr16[p + 3];
        int s4 = (int)csr16[p + 4], s5 = (int)csr16[p + 5];
        int s6 = (int)csr16[p + 6], s7 = (int)csr16[p + 7];
        bf16x8 h0 = *(const bf16x8*)(Hrow + (size_t)s0 * D_H);
        bf16x8 h1 = *(const bf16x8*)(Hrow + (size_t)s1 * D_H);
        bf16x8 h2 = *(const bf16x8*)(Hrow + (size_t)s2 * D_H);
        bf16x8 h3 = *(const bf16x8*)(Hrow + (size_t)s3 * D_H);
        bf16x8 h4 = *(const bf16x8*)(Hrow + (size_t)s4 * D_H);
        bf16x8 h5 = *(const bf16x8*)(Hrow + (size_t)s5 * D_H);
        bf16x8 h6 = *(const bf16x8*)(Hrow + (size_t)s6 * D_H);
        bf16x8 h7 = *(const bf16x8*)(Hrow + (size_t)s7 * D_H);
#pragma unroll
        for (int j = 0; j < 8; j++) {
            a0[j] += (float)h0[j] + (float)h4[j];
            a1[j] += (float)h1[j] + (float)h5[j];
            a2[j] += (float)h2[j] + (float)h6[j];
            a3[j] += (float)h3[j] + (float)h7[j];
        }
    }
    if (p + 4 <= p1) {
        int s0 = (int)csr16[p + 0], s1 = (int)csr16[p + 1];
        int s2 = (int)csr16[p + 2], s3 = (int)csr16[p + 3];
        bf16x8 h0 = *(const bf16x8*)(Hrow + (size_t)s0 * D_H);
        bf16x8 h1 = *(const bf16x8*)(Hrow + (size_t)s1 * D_H);
        bf16x8 h2 = *(const bf16x8*)(Hrow + (size_t)s2 * D_H);
        bf16x8 h3 = *(const bf16x8*)(Hrow + (size_t)s3 * D_H);
#pragma unroll
        for (int j = 0; j < 8; j++) {
            a0[j] += (float)h0[j];
            a1[j] += (float)h1[j];
            a2[j] += (float)h2[j];
            a3[j] += (float)h3[j];
        }
        p += 4;
    }
    if (p + 2 <= p1) {
        int s0 = (int)csr16[p + 0], s1 = (int)csr16[p + 1];
        bf16x8 h0 = *(const bf16x8*)(Hrow + (size_t)s0 * D_H);
        bf16x8 h1 = *(const bf16x8*)(Hrow + (size_t)s1 * D_H);
#pragma unroll
        for (int j = 0; j < 8; j++) { a0[j] += (float)h0[j]; a1[j] += (float)h1[j]; }
        p += 2;
    }
    if (p < p1) {
        int s0 = (int)csr16[p];
        bf16x8 h0 = *(const bf16x8*)(Hrow + (size_t)s0 * D_H);
#pragma unroll
        for (int j = 0; j < 8; j++) a2[j] += (float)h0[j];
    }

    float sum[8];
#pragma unroll
    for (int j = 0; j < 8; j++) sum[j] = (a0[j] + a1[j]) + (a2[j] + a3[j]);

    const float  di = dis[node];
    const float4 b0 = bias4[lane * 2];
    const float4 b1 = bias4[lane * 2 + 1];
    float v0 = fmaf(di, sum[0], b0.x), v1 = fmaf(di, sum[1], b0.y);
    float v2 = fmaf(di, sum[2], b0.z), v3 = fmaf(di, sum[3], b0.w);
    float v4 = fmaf(di, sum[4], b1.x), v5 = fmaf(di, sum[5], b1.y);
    float v6 = fmaf(di, sum[6], b1.z), v7 = fmaf(di, sum[7], b1.w);

    if (mode == 1) {
        v0 = fmaxf(v0, 0.f); v1 = fmaxf(v1, 0.f); v2 = fmaxf(v2, 0.f); v3 = fmaxf(v3, 0.f);
        v4 = fmaxf(v4, 0.f); v5 = fmaxf(v5, 0.f); v6 = fmaxf(v6, 0.f); v7 = fmaxf(v7, 0.f);
        bf16_t h0 = (bf16_t)v0, h1 = (bf16_t)v1, h2 = (bf16_t)v2, h3 = (bf16_t)v3;
        bf16_t h4 = (bf16_t)v4, h5 = (bf16_t)v5, h6 = (bf16_t)v6, h7 = (bf16_t)v7;
        *(bf16x8*)(outH + (size_t)node * D_H + lane * 8) =
            (bf16x8){h0, h1, h2, h3, h4, h5, h6, h7};
        *(bf16x8*)(outL + (size_t)node * D_H + lane * 8) =
            (bf16x8){(bf16_t)(v0 - (float)h0), (bf16_t)(v1 - (float)h1),
                     (bf16_t)(v2 - (float)h2), (bf16_t)(v3 - (float)h3),
                     (bf16_t)(v4 - (float)h4), (bf16_t)(v5 - (float)h5),
                     (bf16_t)(v6 - (float)h6), (bf16_t)(v7 - (float)h7)};
    } else {
        outF[(size_t)node * 32 + lane * 2]     = make_float4(v0, v1, v2, v3);
        outF[(size_t)node * 32 + lane * 2 + 1] = make_float4(v4, v5, v6, v7);
    }
}

extern "C" void kernel_launch(void* const* d_in, const int* in_sizes, int n_in,
                              void* d_out, int out_size, void* d_ws, size_t ws_size,
                              hipStream_t stream) {
    const float* X  = (const float*)d_in[0];
    const int*   ei = (const int*)d_in[1];
    const float* W1 = (const float*)d_in[2];
    const float* b1 = (const float*)d_in[3];
    const float* W2 = (const float*)d_in[4];
    const float* b2 = (const float*)d_in[5];
    float* out = (float*)d_out;

    const int N  = in_sizes[0] / 256;   // 50000
    const int E  = in_sizes[1] / 2;     // 800000
    const int K1 = 256;

    const int* src = ei;
    const int* dst = ei + E;

    uintptr_t p = (uintptr_t)d_ws;
    auto carve = [&](size_t bytes) {
        uintptr_t q = p;
        p += (bytes + 255) & ~(size_t)255;
        return q;
    };
    int*    cnt4  = (int*)carve((size_t)N * 4 * 4);     // 4 privatized copies
    int*    off   = (int*)carve((size_t)(N + 1) * 4);
    int*    offc  = (int*)carve((size_t)N * 4 * 4);     // per-copy bases
    int*    bsums = (int*)carve(64 * 4);
    float*  dis   = (float*)carve((size_t)N * 4);
    u16*    rank  = (u16*)carve((size_t)E * 2);
    u16*    csr16 = (u16*)carve((size_t)E * 2);
    bf16_t* Hb    = (bf16_t*)carve((size_t)N * D_H * 2);
    bf16_t* X1h   = (bf16_t*)carve((size_t)N * D_H * 2);
    bf16_t* X1l   = (bf16_t*)carve((size_t)N * D_H * 2);
    bf16_t* W1h   = (bf16_t*)carve((size_t)K1 * D_H * 2);
    bf16_t* W1l   = (bf16_t*)carve((size_t)K1 * D_H * 2);
    bf16_t* W2h   = (bf16_t*)carve((size_t)D_H * D_H * 2);
    bf16_t* W2l   = (bf16_t*)carve((size_t)D_H * D_H * 2);

    const int nb = (N + 1023) / 1024;

    // fused pre-pass: 4-way privatized countrank + weight prep
    hipMemsetAsync(cnt4, 0, (size_t)N * 4 * 4, stream);
    const int gcr = (E + 255) / 256;
    const int gw  = (K1 * 128 + D_H * 128 + 255) / 256;
    k_pre<<<gcr + gw, 256, 0, stream>>>(dst, cnt4, rank, E, N, gcr,
                                        W1, W1h, W1l, K1,
                                        W2, W2h, W2l, D_H);
    k_scan1<<<nb, 1024, 0, stream>>>(cnt4, off, bsums, dis, N);
    k_scan2<<<1, 64, 0, stream>>>(bsums, nb);
    k_scan3<<<nb, 1024, 0, stream>>>(off, bsums, cnt4, offc, N, E);

    const int gmm = ((N + 63) / 64) * 2;    // 1564 blocks (row x col split)
    const int gag = (N + 15) / 16;          // 3125 agg blocks

    // layer 1 GEMM (reg-prefetch pipelined) with atomic-free CSR fill
    k_mm1fill<<<gmm, 256, 0, stream>>>(X, W1h, W1l, dis, Hb, N, K1,
                                       src, dst, offc, rank, csr16, E, gmm * 256);
    k_agg<<<gag, 256, 0, stream>>>(Hb, dis, off, csr16,
                                   (const float4*)b1, nullptr, X1h, X1l, N, 1);

    // layer 2
    k_mm2<<<gmm, 256, 0, stream>>>(X1h, X1l, W2h, W2l, dis, Hb, N, D_H);
    k_agg<<<gag, 256, 0, stream>>>(Hb, dis, off, csr16,
                                   (const float4*)b2, (float4*)out, nullptr, nullptr, N, 0);
}

// Round 3
// 249.886 us; speedup vs baseline: 1.0313x; 1.0313x over previous
//
#include <hip/hip_runtime.h>
#include <hip/hip_bf16.h>
#include <stdint.h>

#define D_H 128

typedef __bf16 bf16_t;
typedef unsigned short u16;
typedef bf16_t bf16x8 __attribute__((ext_vector_type(8)));
typedef bf16_t bf16x4 __attribute__((ext_vector_type(4)));
typedef float  f32x4  __attribute__((ext_vector_type(4)));

// ------- fused pre-pass: 4-way privatized countrank + W prep ---------------
__global__ void k_pre(const int* __restrict__ dst, int* __restrict__ cnt4,
                      u16* __restrict__ rank, int E, int Nn, int gcr,
                      const float* __restrict__ W1, bf16_t* __restrict__ W1h,
                      bf16_t* __restrict__ W1l, int K1,
                      const float* __restrict__ W2, bf16_t* __restrict__ W2h,
                      bf16_t* __restrict__ W2l, int K2) {
    int bx = (int)blockIdx.x;
    if (bx < gcr) {
        int e = bx * 256 + threadIdx.x;
        if (e < E) {
            int d = dst[e];
            rank[e] = (u16)atomicAdd(&cnt4[(bx & 3) * Nn + d], 1);
        }
        return;
    }
    int id = (bx - gcr) * 256 + threadIdx.x;
    int n1 = K1 * 128;
    if (id < n1) {
        int k = id >> 7, n = id & 127;
        float w = W1[id];
        bf16_t h = (bf16_t)w;
        W1h[(size_t)n * K1 + k] = h;
        W1l[(size_t)n * K1 + k] = (bf16_t)(w - (float)h);
    } else if (id < n1 + K2 * 128) {
        int id2 = id - n1;
        int k = id2 >> 7, n = id2 & 127;
        float w = W2[id2];
        bf16_t h = (bf16_t)w;
        W2h[(size_t)n * K2 + k] = h;
        W2l[(size_t)n * K2 + k] = (bf16_t)(w - (float)h);
    }
}

// ---------------- exclusive scan; scan1 sums the 4 copies + emits dis ------
__global__ __launch_bounds__(1024) void k_scan1(const int* __restrict__ cnt4,
                                                int* __restrict__ out,
                                                int* __restrict__ bsums,
                                                float* __restrict__ dis, int N) {
    __shared__ int tmp[1024];
    int t = threadIdx.x;
    int i = blockIdx.x * 1024 + t;
    int v = 0;
    if (i < N) {
        v = cnt4[i] + cnt4[N + i] + cnt4[2 * N + i] + cnt4[3 * N + i];
        dis[i] = 1.0f / sqrtf((float)(v + 1));
    }
    tmp[t] = v;
    __syncthreads();
    for (int d = 1; d < 1024; d <<= 1) {
        int x = (t >= d) ? tmp[t - d] : 0;
        __syncthreads();
        tmp[t] += x;
        __syncthreads();
    }
    if (i < N) out[i] = tmp[t] - v;
    if (t == 1023) bsums[blockIdx.x] = tmp[t];
}

__global__ void k_scan2(int* __restrict__ bsums, int nb) {
    __shared__ int tmp[64];
    int t = threadIdx.x;
    int v = (t < nb) ? bsums[t] : 0;
    tmp[t] = v;
    __syncthreads();
    for (int d = 1; d < 64; d <<= 1) {
        int x = (t >= d) ? tmp[t - d] : 0;
        __syncthreads();
        tmp[t] += x;
        __syncthreads();
    }
    if (t < nb) bsums[t] = tmp[t] - v;
}

__global__ __launch_bounds__(1024) void k_scan3(int* __restrict__ off,
                                                const int* __restrict__ bsums,
                                                const int* __restrict__ cnt4,
                                                int* __restrict__ offc,
                                                int N, int E) {
    int i = blockIdx.x * 1024 + threadIdx.x;
    if (i < N) {
        int o = off[i] + bsums[blockIdx.x];
        off[i] = o;
        int c0 = cnt4[i], c1 = cnt4[N + i], c2 = cnt4[2 * N + i];
        offc[i]         = o;
        offc[N + i]     = o + c0;
        offc[2 * N + i] = o + c0 + c1;
        offc[3 * N + i] = o + c0 + c1 + c2;
    }
    if (i == 0) off[N] = E;
}

// ---------------- MFMA GEMM tiles: BM=64, BN=128, 512 thr = 8 waves -------
// v11: R0's proven 2-barrier K-loop schedule, but full-D_H column tile:
// A staged ONCE per row-tile (was twice), half the block instances, same
// 24 waves/CU TLP (3 blocks x 8 waves co-resident; LDS 30.7KB < cap).
#define LDK 40
#define FILL_PER 2

// layer-1 (fp32 A, hi/lo split in-kernel, K=256) + atomic-free CSR fill
__global__ __launch_bounds__(512) void k_mm1fill(
        const float* __restrict__ Af,
        const bf16_t* __restrict__ Wh, const bf16_t* __restrict__ Wl,
        const float* __restrict__ dis, bf16_t* __restrict__ Cb,
        int N, int K,
        const int* __restrict__ src, const int* __restrict__ dst,
        const int* __restrict__ offc, const u16* __restrict__ rank,
        u16* __restrict__ csr16, int E, int totThreads) {
    __shared__ bf16_t AsH[64][LDK];
    __shared__ bf16_t AsL[64][LDK];
    __shared__ bf16_t BsH[128][LDK];
    __shared__ bf16_t BsL[128][LDK];

    const int t    = threadIdx.x;
    const int lane = t & 63;
    const int wave = t >> 6;            // 0..7
    const int row0 = (int)blockIdx.x * 64;
    const int wm   = (wave & 1) * 32;   // 2 row-tiles of 32
    const int wn   = (wave >> 1) * 32;  // 4 col-tiles of 32
    const int fm   = lane & 15;
    const int fq   = lane >> 4;

    const int ar  = t >> 3;             // 0..63 (A: 1 float4/thread)
    const int ac4 = t & 7;
    const int br  = t >> 2;             // 0..127 (B: 1 bf16x8/plane/thread)
    const int bc8 = t & 3;

    // ---- fill prologue: resolve scatter addresses ----
    const int g = (int)blockIdx.x * 512 + t;
    int epos[FILL_PER];
    u16 esrc[FILL_PER];
#pragma unroll
    for (int i = 0; i < FILL_PER; i++) {
        int e = g + i * totThreads;
        if (e < E) {
            int d    = dst[e];
            int copy = (e >> 8) & 3;
            epos[i] = offc[copy * N + d] + (int)rank[e];
            esrc[i] = (u16)src[e];
        } else {
            epos[i] = -1;
            esrc[i] = 0;
        }
    }

    f32x4 acc[2][2] = {};

    for (int k0 = 0; k0 < K; k0 += 32) {
        __syncthreads();
        // stage A: 64 rows x 32 k fp32 = 512 float4; 1/thread, split hi/lo
        {
            int gr = row0 + ar;
            float4 v = make_float4(0.f, 0.f, 0.f, 0.f);
            if (gr < N) v = *(const float4*)(Af + (size_t)gr * 256 + k0 + ac4 * 4);
            bf16_t h0 = (bf16_t)v.x, h1 = (bf16_t)v.y, h2 = (bf16_t)v.z, h3 = (bf16_t)v.w;
            *(bf16x4*)&AsH[ar][ac4 * 4] = (bf16x4){h0, h1, h2, h3};
            *(bf16x4*)&AsL[ar][ac4 * 4] =
                (bf16x4){(bf16_t)(v.x - (float)h0), (bf16_t)(v.y - (float)h1),
                         (bf16_t)(v.z - (float)h2), (bf16_t)(v.w - (float)h3)};
        }
        // stage B: 128 cols x 32 k; 1 bf16x8 per plane per thread
        *(bf16x8*)&BsH[br][bc8 * 8] = *(const bf16x8*)(Wh + (size_t)br * 256 + k0 + bc8 * 8);
        *(bf16x8*)&BsL[br][bc8 * 8] = *(const bf16x8*)(Wl + (size_t)br * 256 + k0 + bc8 * 8);
        __syncthreads();

        bf16x8 ah[2], al[2], bh[2], bl[2];
#pragma unroll
        for (int i = 0; i < 2; i++) {
            ah[i] = *(const bf16x8*)&AsH[wm + i * 16 + fm][fq * 8];
            al[i] = *(const bf16x8*)&AsL[wm + i * 16 + fm][fq * 8];
            bh[i] = *(const bf16x8*)&BsH[wn + i * 16 + fm][fq * 8];
            bl[i] = *(const bf16x8*)&BsL[wn + i * 16 + fm][fq * 8];
        }
#pragma unroll
        for (int mi = 0; mi < 2; mi++)
#pragma unroll
            for (int ni = 0; ni < 2; ni++) {
                acc[mi][ni] = __builtin_amdgcn_mfma_f32_16x16x32_bf16(ah[mi], bh[ni], acc[mi][ni], 0, 0, 0);
                acc[mi][ni] = __builtin_amdgcn_mfma_f32_16x16x32_bf16(ah[mi], bl[ni], acc[mi][ni], 0, 0, 0);
                acc[mi][ni] = __builtin_amdgcn_mfma_f32_16x16x32_bf16(al[mi], bh[ni], acc[mi][ni], 0, 0, 0);
            }
    }

#pragma unroll
    for (int mi = 0; mi < 2; mi++)
#pragma unroll
        for (int r = 0; r < 4; r++) {
            int grow = row0 + wm + mi * 16 + fq * 4 + r;
            if (grow < N) {
                float dr = dis[grow];
#pragma unroll
                for (int ni = 0; ni < 2; ni++)
                    Cb[(size_t)grow * D_H + wn + ni * 16 + fm] = (bf16_t)(dr * acc[mi][ni][r]);
            }
        }

    // ---- fill epilogue: scattered 2B stores, fire and forget ----
#pragma unroll
    for (int i = 0; i < FILL_PER; i++)
        if (epos[i] >= 0) csr16[epos[i]] = esrc[i];
}

// layer-2 (bf16 hi/lo A, K=128), same BM=64/BN=128/512-thread structure
__global__ __launch_bounds__(512) void k_mm2(const bf16_t* __restrict__ Ah,
                                             const bf16_t* __restrict__ Al,
                                             const bf16_t* __restrict__ Wh,
                                             const bf16_t* __restrict__ Wl,
                                             const float* __restrict__ dis,
                                             bf16_t* __restrict__ Cb,
                                             int N, int K) {
    __shared__ bf16_t AsH[64][LDK];
    __shared__ bf16_t AsL[64][LDK];
    __shared__ bf16_t BsH[128][LDK];
    __shared__ bf16_t BsL[128][LDK];

    const int t    = threadIdx.x;
    const int lane = t & 63;
    const int wave = t >> 6;
    const int row0 = (int)blockIdx.x * 64;
    const int wm   = (wave & 1) * 32;
    const int wn   = (wave >> 1) * 32;
    const int fm   = lane & 15;
    const int fq   = lane >> 4;

    // A staging: 64 rows x 2 planes x 4 chunks = 512 assignments (1/thread)
    const int arow = t >> 3;            // 0..63
    const int apl  = (t >> 2) & 1;      // plane: 0=H 1=L
    const int ac8  = t & 3;
    // B staging: 128 rows x 4 chunks, both planes (2/thread)
    const int br   = t >> 2;            // 0..127
    const int bc8  = t & 3;

    f32x4 acc[2][2] = {};

    for (int k0 = 0; k0 < K; k0 += 32) {
        __syncthreads();
        {
            int gr = row0 + arow;
            bf16x8 va = {};
            const bf16_t* Ap = apl ? Al : Ah;
            if (gr < N) va = *(const bf16x8*)(Ap + (size_t)gr * 128 + k0 + ac8 * 8);
            if (apl) *(bf16x8*)&AsL[arow][ac8 * 8] = va;
            else     *(bf16x8*)&AsH[arow][ac8 * 8] = va;
        }
        *(bf16x8*)&BsH[br][bc8 * 8] = *(const bf16x8*)(Wh + (size_t)br * 128 + k0 + bc8 * 8);
        *(bf16x8*)&BsL[br][bc8 * 8] = *(const bf16x8*)(Wl + (size_t)br * 128 + k0 + bc8 * 8);
        __syncthreads();

        bf16x8 ah[2], al[2], bh[2], bl[2];
#pragma unroll
        for (int i = 0; i < 2; i++) {
            ah[i] = *(const bf16x8*)&AsH[wm + i * 16 + fm][fq * 8];
            al[i] = *(const bf16x8*)&AsL[wm + i * 16 + fm][fq * 8];
            bh[i] = *(const bf16x8*)&BsH[wn + i * 16 + fm][fq * 8];
            bl[i] = *(const bf16x8*)&BsL[wn + i * 16 + fm][fq * 8];
        }
#pragma unroll
        for (int mi = 0; mi < 2; mi++)
#pragma unroll
            for (int ni = 0; ni < 2; ni++) {
                acc[mi][ni] = __builtin_amdgcn_mfma_f32_16x16x32_bf16(ah[mi], bh[ni], acc[mi][ni], 0, 0, 0);
                acc[mi][ni] = __builtin_amdgcn_mfma_f32_16x16x32_bf16(ah[mi], bl[ni], acc[mi][ni], 0, 0, 0);
                acc[mi][ni] = __builtin_amdgcn_mfma_f32_16x16x32_bf16(al[mi], bh[ni], acc[mi][ni], 0, 0, 0);
            }
    }

#pragma unroll
    for (int mi = 0; mi < 2; mi++)
#pragma unroll
        for (int r = 0; r < 4; r++) {
            int grow = row0 + wm + mi * 16 + fq * 4 + r;
            if (grow < N) {
                float dr = dis[grow];
#pragma unroll
                for (int ni = 0; ni < 2; ni++)
                    Cb[(size_t)grow * D_H + wn + ni * 16 + fm] = (bf16_t)(dr * acc[mi][ni][r]);
            }
        }
}

// ---------------- aggregation (16 lanes/node x bf16x8 = 16B/lane) ----------
__global__ __launch_bounds__(256) void k_agg(const bf16_t* __restrict__ Hb,
                                             const float* __restrict__ dis,
                                             const int* __restrict__ off,
                                             const u16* __restrict__ csr16,
                                             const float4* __restrict__ bias4,
                                             float4* __restrict__ outF,
                                             bf16_t* __restrict__ outH,
                                             bf16_t* __restrict__ outL,
                                             int N, int mode) {
    const int slot = threadIdx.x >> 4;           // 0..15: node slot
    const int lane = threadIdx.x & 15;           // feature group (8 bf16 = 16B)
    const int node = blockIdx.x * 16 + slot;
    if (node >= N) return;

    const bf16_t* Hrow = Hb + (size_t)lane * 8;

    float a0[8], a1[8], a2[8], a3[8];
    {
        bf16x8 v = *(const bf16x8*)(Hrow + (size_t)node * D_H);
#pragma unroll
        for (int j = 0; j < 8; j++) { a0[j] = (float)v[j]; a1[j] = 0.f; a2[j] = 0.f; a3[j] = 0.f; }
    }

    int p  = off[node];
    int p1 = off[node + 1];

    for (; p + 4 <= p1; p += 4) {
        int s0 = (int)csr16[p + 0], s1 = (int)csr16[p + 1];
        int s2 = (int)csr16[p + 2], s3 = (int)csr16[p + 3];
        bf16x8 h0 = *(const bf16x8*)(Hrow + (size_t)s0 * D_H);
        bf16x8 h1 = *(const bf16x8*)(Hrow + (size_t)s1 * D_H);
        bf16x8 h2 = *(const bf16x8*)(Hrow + (size_t)s2 * D_H);
        bf16x8 h3 = *(const bf16x8*)(Hrow + (size_t)s3 * D_H);
#pragma unroll
        for (int j = 0; j < 8; j++) {
            a0[j] += (float)h0[j];
            a1[j] += (float)h1[j];
            a2[j] += (float)h2[j];
            a3[j] += (float)h3[j];
        }
    }
    if (p + 2 <= p1) {
        int s0 = (int)csr16[p + 0], s1 = (int)csr16[p + 1];
        bf16x8 h0 = *(const bf16x8*)(Hrow + (size_t)s0 * D_H);
        bf16x8 h1 = *(const bf16x8*)(Hrow + (size_t)s1 * D_H);
#pragma unroll
        for (int j = 0; j < 8; j++) { a0[j] += (float)h0[j]; a1[j] += (float)h1[j]; }
        p += 2;
    }
    if (p < p1) {
        int s0 = (int)csr16[p];
        bf16x8 h0 = *(const bf16x8*)(Hrow + (size_t)s0 * D_H);
#pragma unroll
        for (int j = 0; j < 8; j++) a2[j] += (float)h0[j];
    }

    float sum[8];
#pragma unroll
    for (int j = 0; j < 8; j++) sum[j] = (a0[j] + a1[j]) + (a2[j] + a3[j]);

    const float  di = dis[node];
    const float4 b0 = bias4[lane * 2];
    const float4 b1 = bias4[lane * 2 + 1];
    float v0 = fmaf(di, sum[0], b0.x), v1 = fmaf(di, sum[1], b0.y);
    float v2 = fmaf(di, sum[2], b0.z), v3 = fmaf(di, sum[3], b0.w);
    float v4 = fmaf(di, sum[4], b1.x), v5 = fmaf(di, sum[5], b1.y);
    float v6 = fmaf(di, sum[6], b1.z), v7 = fmaf(di, sum[7], b1.w);

    if (mode == 1) {
        v0 = fmaxf(v0, 0.f); v1 = fmaxf(v1, 0.f); v2 = fmaxf(v2, 0.f); v3 = fmaxf(v3, 0.f);
        v4 = fmaxf(v4, 0.f); v5 = fmaxf(v5, 0.f); v6 = fmaxf(v6, 0.f); v7 = fmaxf(v7, 0.f);
        bf16_t h0 = (bf16_t)v0, h1 = (bf16_t)v1, h2 = (bf16_t)v2, h3 = (bf16_t)v3;
        bf16_t h4 = (bf16_t)v4, h5 = (bf16_t)v5, h6 = (bf16_t)v6, h7 = (bf16_t)v7;
        *(bf16x8*)(outH + (size_t)node * D_H + lane * 8) =
            (bf16x8){h0, h1, h2, h3, h4, h5, h6, h7};
        *(bf16x8*)(outL + (size_t)node * D_H + lane * 8) =
            (bf16x8){(bf16_t)(v0 - (float)h0), (bf16_t)(v1 - (float)h1),
                     (bf16_t)(v2 - (float)h2), (bf16_t)(v3 - (float)h3),
                     (bf16_t)(v4 - (float)h4), (bf16_t)(v5 - (float)h5),
                     (bf16_t)(v6 - (float)h6), (bf16_t)(v7 - (float)h7)};
    } else {
        outF[(size_t)node * 32 + lane * 2]     = make_float4(v0, v1, v2, v3);
        outF[(size_t)node * 32 + lane * 2 + 1] = make_float4(v4, v5, v6, v7);
    }
}

extern "C" void kernel_launch(void* const* d_in, const int* in_sizes, int n_in,
                              void* d_out, int out_size, void* d_ws, size_t ws_size,
                              hipStream_t stream) {
    const float* X  = (const float*)d_in[0];
    const int*   ei = (const int*)d_in[1];
    const float* W1 = (const float*)d_in[2];
    const float* b1 = (const float*)d_in[3];
    const float* W2 = (const float*)d_in[4];
    const float* b2 = (const float*)d_in[5];
    float* out = (float*)d_out;

    const int N  = in_sizes[0] / 256;   // 50000
    const int E  = in_sizes[1] / 2;     // 800000
    const int K1 = 256;

    const int* src = ei;
    const int* dst = ei + E;

    uintptr_t p = (uintptr_t)d_ws;
    auto carve = [&](size_t bytes) {
        uintptr_t q = p;
        p += (bytes + 255) & ~(size_t)255;
        return q;
    };
    int*    cnt4  = (int*)carve((size_t)N * 4 * 4);     // 4 privatized copies
    int*    off   = (int*)carve((size_t)(N + 1) * 4);
    int*    offc  = (int*)carve((size_t)N * 4 * 4);     // per-copy bases
    int*    bsums = (int*)carve(64 * 4);
    float*  dis   = (float*)carve((size_t)N * 4);
    u16*    rank  = (u16*)carve((size_t)E * 2);
    u16*    csr16 = (u16*)carve((size_t)E * 2);
    bf16_t* Hb    = (bf16_t*)carve((size_t)N * D_H * 2);
    bf16_t* X1h   = (bf16_t*)carve((size_t)N * D_H * 2);
    bf16_t* X1l   = (bf16_t*)carve((size_t)N * D_H * 2);
    bf16_t* W1h   = (bf16_t*)carve((size_t)K1 * D_H * 2);
    bf16_t* W1l   = (bf16_t*)carve((size_t)K1 * D_H * 2);
    bf16_t* W2h   = (bf16_t*)carve((size_t)D_H * D_H * 2);
    bf16_t* W2l   = (bf16_t*)carve((size_t)D_H * D_H * 2);

    const int nb = (N + 1023) / 1024;

    // fused pre-pass: 4-way privatized countrank + weight prep
    hipMemsetAsync(cnt4, 0, (size_t)N * 4 * 4, stream);
    const int gcr = (E + 255) / 256;
    const int gw  = (K1 * 128 + D_H * 128 + 255) / 256;
    k_pre<<<gcr + gw, 256, 0, stream>>>(dst, cnt4, rank, E, N, gcr,
                                        W1, W1h, W1l, K1,
                                        W2, W2h, W2l, D_H);
    k_scan1<<<nb, 1024, 0, stream>>>(cnt4, off, bsums, dis, N);
    k_scan2<<<1, 64, 0, stream>>>(bsums, nb);
    k_scan3<<<nb, 1024, 0, stream>>>(off, bsums, cnt4, offc, N, E);

    const int gmm = (N + 63) / 64;          // 782 blocks (full-width col tile)
    const int gag = (N + 15) / 16;          // 3125 agg blocks

    // layer 1 GEMM (BM=64 x BN=128, 512 thr) with atomic-free CSR fill
    k_mm1fill<<<gmm, 512, 0, stream>>>(X, W1h, W1l, dis, Hb, N, K1,
                                       src, dst, offc, rank, csr16, E, gmm * 512);
    k_agg<<<gag, 256, 0, stream>>>(Hb, dis, off, csr16,
                                   (const float4*)b1, nullptr, X1h, X1l, N, 1);

    // layer 2
    k_mm2<<<gmm, 512, 0, stream>>>(X1h, X1l, W2h, W2l, dis, Hb, N, D_H);
    k_agg<<<gag, 256, 0, stream>>>(Hb, dis, off, csr16,
                                   (const float4*)b2, (float4*)out, nullptr, nullptr, N, 0);
}